// Round 4
// baseline (2052.504 us; speedup 1.0000x reference)
//
#include <hip/hip_runtime.h>

constexpr int NN = 120000;
constexpr int EE = 1200000;
constexpr float EPSV = 1e-5f;
constexpr int NB_SCAN = (NN + 255) / 256;   // 469

// ---------------- CSR build ----------------
__global__ __launch_bounds__(256) void k_count(const int* __restrict__ dst, int* __restrict__ cnt){
  int e = blockIdx.x*256 + threadIdx.x;
  if (e < EE) atomicAdd(&cnt[dst[e]], 1);
}

__global__ __launch_bounds__(256) void k_scan1(const int* __restrict__ cnt, int* __restrict__ pre,
                                               int* __restrict__ blksum){
  __shared__ int sm[256];
  int i = blockIdx.x*256 + threadIdx.x;
  int v = (i < NN) ? cnt[i] : 0;
  sm[threadIdx.x] = v; __syncthreads();
  for (int off = 1; off < 256; off <<= 1){
    int t = (threadIdx.x >= off) ? sm[threadIdx.x - off] : 0;
    __syncthreads();
    sm[threadIdx.x] += t;
    __syncthreads();
  }
  if (i < NN) pre[i] = sm[threadIdx.x] - v;
  if (threadIdx.x == 255) blksum[blockIdx.x] = sm[255];
}

__global__ __launch_bounds__(512) void k_scan2(int* __restrict__ blksum){
  __shared__ int sm[512];
  int v = (threadIdx.x < NB_SCAN) ? blksum[threadIdx.x] : 0;
  sm[threadIdx.x] = v; __syncthreads();
  for (int off = 1; off < 512; off <<= 1){
    int t = (threadIdx.x >= off) ? sm[threadIdx.x - off] : 0;
    __syncthreads();
    sm[threadIdx.x] += t;
    __syncthreads();
  }
  if (threadIdx.x < NB_SCAN) blksum[threadIdx.x] = sm[threadIdx.x] - v;
}

__global__ __launch_bounds__(256) void k_scan3(const int* __restrict__ pre, const int* __restrict__ blksum,
                                               const int* __restrict__ cnt,
                                               int* __restrict__ row_ptr, int* __restrict__ cursor,
                                               float* __restrict__ invdeg){
  int i = blockIdx.x*256 + threadIdx.x;
  if (i < NN){
    int r = pre[i] + blksum[blockIdx.x];
    row_ptr[i] = r; cursor[i] = r;
    int c = cnt[i];
    invdeg[i] = (c > 0) ? (1.0f/(float)c) : -1.0f;
  }
}

__global__ __launch_bounds__(256) void k_fill(const int* __restrict__ src, const int* __restrict__ dst,
                                              int* __restrict__ cursor, int* __restrict__ adj){
  int e = blockIdx.x*256 + threadIdx.x;
  if (e < EE){
    int p = atomicAdd(&cursor[dst[e]], 1);
    adj[p] = src[e];
  }
}

// ---------------- Aggregation: gather by destination ----------------
__global__ __launch_bounds__(256) void k_gather64(const float* __restrict__ x, const int* __restrict__ row_ptr,
                                                  const int* __restrict__ cnt, const int* __restrict__ adj,
                                                  float* __restrict__ agg){
  const int lane = threadIdx.x & 63;
  const int wave = blockIdx.x*4 + (threadIdx.x >> 6);
  const int nwav = gridDim.x*4;
  for (int n = wave; n < NN; n += nwav){
    int st = row_ptr[n], d = cnt[n];
    float acc = 0.0f;
    int j = 0;
    for (; j + 1 < d; j += 2){
      int s0 = adj[st+j], s1 = adj[st+j+1];
      float v0 = x[(size_t)s0*64 + lane];
      float v1 = x[(size_t)s1*64 + lane];
      acc += v0 + v1;
    }
    if (j < d){
      int s0 = adj[st+j];
      acc += x[(size_t)s0*64 + lane];
    }
    agg[(size_t)n*64 + lane] = acc;
  }
}

__global__ __launch_bounds__(256) void k_gather14(const float* __restrict__ x, const int* __restrict__ row_ptr,
                                                  const int* __restrict__ cnt, const int* __restrict__ adj,
                                                  float* __restrict__ agg){
  const int lane = threadIdx.x & 63;
  const int f = lane & 15, g = lane >> 4;
  const int wave = blockIdx.x*4 + (threadIdx.x >> 6);
  const int nwav = gridDim.x*4;
  for (int n = wave; n < NN; n += nwav){
    int st = row_ptr[n], d = cnt[n];
    float acc = 0.0f;
    for (int j = g; j < d; j += 4){
      int s = adj[st+j];
      if (f < 14) acc += x[(size_t)s*14 + f];
    }
    acc += __shfl_down(acc, 32);
    acc += __shfl_down(acc, 16);
    if (lane < 14) agg[(size_t)n*14 + lane] = acc;
  }
}

// ---------------- BN-fold weight prep ----------------
__global__ __launch_bounds__(256) void k_prep(const float* __restrict__ Wn, const float* __restrict__ Wr,
                                              const float* __restrict__ b, const float* __restrict__ stats,
                                              const float* __restrict__ g, const float* __restrict__ be,
                                              float* __restrict__ wbuf, int din){
  __shared__ float sc[64], sh[64];
  int t = threadIdx.x;
  if (t < 64){
    float a = 1.0f, s0 = 0.0f;
    if (stats){
      float m = stats[t] * (1.0f/NN);
      float v = stats[64+t] * (1.0f/NN) - m*m;
      a  = g[t] * rsqrtf(v + EPSV);
      s0 = be[t] - m*a;
    }
    sc[t] = a; sh[t] = s0;
  }
  __syncthreads();
  for (int i = t; i < din*64; i += 256){
    int k = i >> 6;
    wbuf[i]          = sc[k]*Wn[i];
    wbuf[din*64 + i] = sc[k]*Wr[i];
  }
  if (t < 64){
    float accB = b ? b[t] : 0.0f;
    float accN = 0.0f;
    for (int k=0;k<din;k++){
      accB += sh[k]*Wr[k*64+t];
      accN += sh[k]*Wn[k*64+t];
    }
    wbuf[2*din*64 + t]      = accB;
    wbuf[2*din*64 + 64 + t] = accN;
  }
}

// ---------------- conv GEMM, 2 nodes/iter, weights pinned in VGPRs ----------------
template<int DIN, int ACT, bool STATS>
__global__ __launch_bounds__(256, 1) void k_gemm_conv(const float* __restrict__ agg, const float* __restrict__ x,
                                                      const float* __restrict__ invdeg, const float* __restrict__ wbuf,
                                                      float* __restrict__ out, float* __restrict__ stats){
  const int lane  = threadIdx.x & 63;
  const int wave  = blockIdx.x*4 + (threadIdx.x >> 6);
  const int nwav  = gridDim.x*4;
  float wn[DIN], wr[DIN];
  #pragma unroll
  for (int k=0;k<DIN;k++){
    wn[k] = wbuf[k*64+lane];
    wr[k] = wbuf[(DIN+k)*64+lane];
  }
  const float bj0 = wbuf[2*DIN*64+lane];
  const float bj1 = wbuf[2*DIN*64+64+lane];
  float ls = 0.0f, lss = 0.0f;
  // NN is even: pairs always complete
  for (int n0 = wave*2; n0 < NN; n0 += nwav*2){
    const int n1 = n0 + 1;
    float accA0 = 0.0f, accX0 = 0.0f, accA1 = 0.0f, accX1 = 0.0f;
    if constexpr ((DIN & 3) == 0){
      const float4* a0 = (const float4*)(agg + (size_t)n0*DIN);
      const float4* x0 = (const float4*)(x   + (size_t)n0*DIN);
      const float4* a1 = (const float4*)(agg + (size_t)n1*DIN);
      const float4* p1 = (const float4*)(x   + (size_t)n1*DIN);
      #pragma unroll
      for (int c=0;c<DIN/4;c++){
        float4 a = a0[c], b = x0[c], e = a1[c], f = p1[c];
        accA0 = fmaf(a.x, wn[4*c+0], accA0);
        accX0 = fmaf(b.x, wr[4*c+0], accX0);
        accA1 = fmaf(e.x, wn[4*c+0], accA1);
        accX1 = fmaf(f.x, wr[4*c+0], accX1);
        accA0 = fmaf(a.y, wn[4*c+1], accA0);
        accX0 = fmaf(b.y, wr[4*c+1], accX0);
        accA1 = fmaf(e.y, wn[4*c+1], accA1);
        accX1 = fmaf(f.y, wr[4*c+1], accX1);
        accA0 = fmaf(a.z, wn[4*c+2], accA0);
        accX0 = fmaf(b.z, wr[4*c+2], accX0);
        accA1 = fmaf(e.z, wn[4*c+2], accA1);
        accX1 = fmaf(f.z, wr[4*c+2], accX1);
        accA0 = fmaf(a.w, wn[4*c+3], accA0);
        accX0 = fmaf(b.w, wr[4*c+3], accX0);
        accA1 = fmaf(e.w, wn[4*c+3], accA1);
        accX1 = fmaf(f.w, wr[4*c+3], accX1);
      }
    } else {
      const float* a0 = agg + (size_t)n0*DIN;
      const float* x0 = x   + (size_t)n0*DIN;
      const float* a1 = agg + (size_t)n1*DIN;
      const float* p1 = x   + (size_t)n1*DIN;
      #pragma unroll
      for (int k=0;k<DIN;k++){
        accA0 = fmaf(a0[k], wn[k], accA0);
        accX0 = fmaf(x0[k], wr[k], accX0);
        accA1 = fmaf(a1[k], wn[k], accA1);
        accX1 = fmaf(p1[k], wr[k], accX1);
      }
    }
    float iv0 = invdeg[n0], iv1 = invdeg[n1];
    float t0 = (iv0 > 0.0f) ? fmaf(accA0, iv0, bj1) : 0.0f;
    float t1 = (iv1 > 0.0f) ? fmaf(accA1, iv1, bj1) : 0.0f;
    float z0 = accX0 + bj0 + t0;
    float z1 = accX1 + bj0 + t1;
    if (ACT == 1){ z0 = z0 > 0.0f ? z0 : 0.01f*z0; z1 = z1 > 0.0f ? z1 : 0.01f*z1; }
    if (ACT == 2){ z0 = fmaxf(z0, 0.0f); z1 = fmaxf(z1, 0.0f); }
    out[(size_t)n0*64 + lane] = z0;
    out[(size_t)n1*64 + lane] = z1;
    if (STATS){ ls += z0 + z1; lss = fmaf(z0,z0,lss); lss = fmaf(z1,z1,lss); }
  }
  if (STATS){
    atomicAdd(&stats[lane], ls);
    atomicAdd(&stats[64+lane], lss);
  }
}

// ---------------- plain linear, 2 nodes/iter ----------------
template<int DOUT, bool STATS, bool BIAS>
__global__ __launch_bounds__(256, 1) void k_gemm_lin(const float* __restrict__ x, const float* __restrict__ W,
                                                     const float* __restrict__ bias, float* __restrict__ out,
                                                     float* __restrict__ stats){
  const int lane = threadIdx.x & 63;
  const int wave = blockIdx.x*4 + (threadIdx.x >> 6);
  const int nwav = gridDim.x*4;
  if (DOUT < 64 && lane >= DOUT) return;
  float w[64];
  #pragma unroll
  for (int k=0;k<64;k++) w[k] = W[k*DOUT + lane];
  const float bj = BIAS ? bias[lane] : 0.0f;
  float ls = 0.0f, lss = 0.0f;
  for (int n0 = wave*2; n0 < NN; n0 += nwav*2){
    const int n1 = n0 + 1;
    const float4* x0 = (const float4*)(x + (size_t)n0*64);
    const float4* x1 = (const float4*)(x + (size_t)n1*64);
    float a0 = 0.0f, a1 = 0.0f, b0 = 0.0f, b1 = 0.0f;
    #pragma unroll
    for (int c=0;c<8;c++){
      float4 v0 = x0[2*c], v1 = x0[2*c+1], u0 = x1[2*c], u1 = x1[2*c+1];
      a0 = fmaf(v0.x, w[8*c+0], a0);
      b0 = fmaf(v1.x, w[8*c+4], b0);
      a1 = fmaf(u0.x, w[8*c+0], a1);
      b1 = fmaf(u1.x, w[8*c+4], b1);
      a0 = fmaf(v0.y, w[8*c+1], a0);
      b0 = fmaf(v1.y, w[8*c+5], b0);
      a1 = fmaf(u0.y, w[8*c+1], a1);
      b1 = fmaf(u1.y, w[8*c+5], b1);
      a0 = fmaf(v0.z, w[8*c+2], a0);
      b0 = fmaf(v1.z, w[8*c+6], b0);
      a1 = fmaf(u0.z, w[8*c+2], a1);
      b1 = fmaf(u1.z, w[8*c+6], b1);
      a0 = fmaf(v0.w, w[8*c+3], a0);
      b0 = fmaf(v1.w, w[8*c+7], b0);
      a1 = fmaf(u0.w, w[8*c+3], a1);
      b1 = fmaf(u1.w, w[8*c+7], b1);
    }
    float z0 = a0 + b0 + bj;
    float z1 = a1 + b1 + bj;
    out[(size_t)n0*DOUT + lane] = z0;
    out[(size_t)n1*DOUT + lane] = z1;
    if (STATS){ ls += z0 + z1; lss = fmaf(z0,z0,lss); lss = fmaf(z1,z1,lss); }
  }
  if (STATS){ atomicAdd(&stats[lane], ls); atomicAdd(&stats[64+lane], lss); }
}

__global__ __launch_bounds__(256) void k_normrelu(float* __restrict__ h, const float* __restrict__ stats,
                                                  const float* __restrict__ g, const float* __restrict__ be){
  size_t idx = (size_t)blockIdx.x*256 + threadIdx.x;
  int f = (int)(idx & 63);
  float m = stats[f] * (1.0f/NN);
  float v = stats[64+f] * (1.0f/NN) - m*m;
  float a = g[f]*rsqrtf(v+EPSV);
  float b = be[f] - m*a;
  float z = h[idx];
  h[idx] = fmaxf(fmaf(a, z, b), 0.0f);
}

extern "C" void kernel_launch(void* const* d_in, const int* in_sizes, int n_in,
                              void* d_out, int out_size, void* d_ws, size_t ws_size,
                              hipStream_t stream){
  const float* x1  = (const float*)d_in[0];
  const int*   ei  = (const int*)d_in[1];
  const int* srcp = ei;
  const int* dstp = ei + EE;
  const float *Wn1=(const float*)d_in[2],  *Wr1=(const float*)d_in[3],  *b1=(const float*)d_in[4];
  const float *Wn2=(const float*)d_in[5],  *Wr2=(const float*)d_in[6],  *b2=(const float*)d_in[7];
  const float *Wn3=(const float*)d_in[8],  *Wr3=(const float*)d_in[9],  *b3=(const float*)d_in[10];
  const float *Wn4=(const float*)d_in[11], *Wr4=(const float*)d_in[12], *b4=(const float*)d_in[13];
  const float *g1=(const float*)d_in[14], *be1=(const float*)d_in[15];
  const float *g2=(const float*)d_in[16], *be2=(const float*)d_in[17];
  const float *g3=(const float*)d_in[18], *be3=(const float*)d_in[19];
  const float *Wm0=(const float*)d_in[20], *gm0=(const float*)d_in[21], *bem0=(const float*)d_in[22];
  const float *Wm1=(const float*)d_in[23], *gm1=(const float*)d_in[24], *bem1=(const float*)d_in[25];
  const float *Wm2=(const float*)d_in[26], *bm2=(const float*)d_in[27];
  float* out = (float*)d_out;

  char* ws = (char*)d_ws;
  int*   cnt     = (int*)(ws);
  int*   row_ptr = (int*)(ws + (1ull<<20));
  int*   cursor  = (int*)(ws + (2ull<<20));
  int*   pre     = (int*)(ws + (3ull<<20));
  int*   blksum  = (int*)(ws + (4ull<<20));
  float* invdeg  = (float*)(ws + (5ull<<20));
  int*   adj     = (int*)(ws + (6ull<<20));
  float* agg     = (float*)(ws + (12ull<<20));
  float* hA      = (float*)(ws + (43ull<<20));
  float* hB      = (float*)(ws + (74ull<<20));
  float* stats   = (float*)(ws + (105ull<<20));
  float* wbuf    = (float*)(ws + (105ull<<20) + 8192);

  hipMemsetAsync(cnt, 0, NN*sizeof(int), stream);
  hipMemsetAsync(stats, 0, 5*128*sizeof(float), stream);
  k_count<<<(EE+255)/256,256,0,stream>>>(dstp, cnt);
  k_scan1<<<NB_SCAN,256,0,stream>>>(cnt, pre, blksum);
  k_scan2<<<1,512,0,stream>>>(blksum);
  k_scan3<<<NB_SCAN,256,0,stream>>>(pre, blksum, cnt, row_ptr, cursor, invdeg);
  k_fill<<<(EE+255)/256,256,0,stream>>>(srcp, dstp, cursor, adj);

  k_gather14<<<2048,256,0,stream>>>(x1, row_ptr, cnt, adj, agg);
  k_prep<<<1,256,0,stream>>>(Wn1,Wr1,b1,nullptr,nullptr,nullptr,wbuf,14);
  k_gemm_conv<14,1,true><<<2048,256,0,stream>>>(agg,x1,invdeg,wbuf,hA,stats);

  k_gather64<<<2048,256,0,stream>>>(hA, row_ptr, cnt, adj, agg);
  k_prep<<<1,256,0,stream>>>(Wn2,Wr2,b2,stats,g1,be1,wbuf,64);
  k_gemm_conv<64,1,true><<<2048,256,0,stream>>>(agg,hA,invdeg,wbuf,hB,stats+128);

  k_gather64<<<2048,256,0,stream>>>(hB, row_ptr, cnt, adj, agg);
  k_prep<<<1,256,0,stream>>>(Wn3,Wr3,b3,stats+128,g2,be2,wbuf,64);
  k_gemm_conv<64,2,true><<<2048,256,0,stream>>>(agg,hB,invdeg,wbuf,hA,stats+256);

  k_gather64<<<2048,256,0,stream>>>(hA, row_ptr, cnt, adj, agg);
  k_prep<<<1,256,0,stream>>>(Wn4,Wr4,b4,stats+256,g3,be3,wbuf,64);
  k_gemm_conv<64,0,false><<<2048,256,0,stream>>>(agg,hA,invdeg,wbuf,hB,nullptr);

  k_gemm_lin<64,true,false><<<2048,256,0,stream>>>(hB,Wm0,nullptr,hA,stats+384);
  k_normrelu<<<(NN*64)/256,256,0,stream>>>(hA,stats+384,gm0,bem0);
  k_gemm_lin<64,true,false><<<2048,256,0,stream>>>(hA,Wm1,nullptr,hB,stats+512);
  k_normrelu<<<(NN*64)/256,256,0,stream>>>(hB,stats+512,gm1,bem1);
  k_gemm_lin<21,false,true><<<2048,256,0,stream>>>(hB,Wm2,bm2,out,nullptr);
}

// Round 5
// 1051.494 us; speedup vs baseline: 1.9520x; 1.9520x over previous
//
#include <hip/hip_runtime.h>

constexpr int NN = 120000;
constexpr int EE = 1200000;
constexpr float EPSV = 1e-5f;
constexpr int NB_SCAN = (NN + 255) / 256;   // 469
constexpr int NTILE = NN / 64;              // 1875 (exact)

// ---------------- CSR build ----------------
__global__ __launch_bounds__(256) void k_count(const int* __restrict__ dst, int* __restrict__ cnt){
  int e = blockIdx.x*256 + threadIdx.x;
  if (e < EE) atomicAdd(&cnt[dst[e]], 1);
}

__global__ __launch_bounds__(256) void k_scan1(const int* __restrict__ cnt, int* __restrict__ pre,
                                               int* __restrict__ blksum){
  __shared__ int sm[256];
  int i = blockIdx.x*256 + threadIdx.x;
  int v = (i < NN) ? cnt[i] : 0;
  sm[threadIdx.x] = v; __syncthreads();
  for (int off = 1; off < 256; off <<= 1){
    int t = (threadIdx.x >= off) ? sm[threadIdx.x - off] : 0;
    __syncthreads();
    sm[threadIdx.x] += t;
    __syncthreads();
  }
  if (i < NN) pre[i] = sm[threadIdx.x] - v;
  if (threadIdx.x == 255) blksum[blockIdx.x] = sm[255];
}

__global__ __launch_bounds__(512) void k_scan2(int* __restrict__ blksum){
  __shared__ int sm[512];
  int v = (threadIdx.x < NB_SCAN) ? blksum[threadIdx.x] : 0;
  sm[threadIdx.x] = v; __syncthreads();
  for (int off = 1; off < 512; off <<= 1){
    int t = (threadIdx.x >= off) ? sm[threadIdx.x - off] : 0;
    __syncthreads();
    sm[threadIdx.x] += t;
    __syncthreads();
  }
  if (threadIdx.x < NB_SCAN) blksum[threadIdx.x] = sm[threadIdx.x] - v;
}

__global__ __launch_bounds__(256) void k_scan3(const int* __restrict__ pre, const int* __restrict__ blksum,
                                               const int* __restrict__ cnt,
                                               int* __restrict__ row_ptr, int* __restrict__ cursor,
                                               float* __restrict__ invdeg){
  int i = blockIdx.x*256 + threadIdx.x;
  if (i < NN){
    int r = pre[i] + blksum[blockIdx.x];
    row_ptr[i] = r; cursor[i] = r;
    int c = cnt[i];
    invdeg[i] = (c > 0) ? (1.0f/(float)c) : -1.0f;
  }
}

__global__ __launch_bounds__(256) void k_fill(const int* __restrict__ src, const int* __restrict__ dst,
                                              int* __restrict__ cursor, int* __restrict__ adj){
  int e = blockIdx.x*256 + threadIdx.x;
  if (e < EE){
    int p = atomicAdd(&cursor[dst[e]], 1);
    adj[p] = src[e];
  }
}

// ---------------- Aggregation: gather by destination ----------------
__global__ __launch_bounds__(256) void k_gather64(const float* __restrict__ x, const int* __restrict__ row_ptr,
                                                  const int* __restrict__ cnt, const int* __restrict__ adj,
                                                  float* __restrict__ agg){
  const int lane = threadIdx.x & 63;
  const int wave = blockIdx.x*4 + (threadIdx.x >> 6);
  const int nwav = gridDim.x*4;
  for (int n = wave; n < NN; n += nwav){
    int st = row_ptr[n], d = cnt[n];
    float acc = 0.0f;
    int j = 0;
    for (; j + 1 < d; j += 2){
      int s0 = adj[st+j], s1 = adj[st+j+1];
      float v0 = x[(size_t)s0*64 + lane];
      float v1 = x[(size_t)s1*64 + lane];
      acc += v0 + v1;
    }
    if (j < d){
      int s0 = adj[st+j];
      acc += x[(size_t)s0*64 + lane];
    }
    agg[(size_t)n*64 + lane] = acc;
  }
}

__global__ __launch_bounds__(256) void k_gather14(const float* __restrict__ x, const int* __restrict__ row_ptr,
                                                  const int* __restrict__ cnt, const int* __restrict__ adj,
                                                  float* __restrict__ agg){
  const int lane = threadIdx.x & 63;
  const int f = lane & 15, g = lane >> 4;
  const int wave = blockIdx.x*4 + (threadIdx.x >> 6);
  const int nwav = gridDim.x*4;
  for (int n = wave; n < NN; n += nwav){
    int st = row_ptr[n], d = cnt[n];
    float acc = 0.0f;
    for (int j = g; j < d; j += 4){
      int s = adj[st+j];
      if (f < 14) acc += x[(size_t)s*14 + f];
    }
    acc += __shfl_down(acc, 32);
    acc += __shfl_down(acc, 16);
    if (lane < 14) agg[(size_t)n*14 + lane] = acc;
  }
}

// ---------------- BN-fold weight prep ----------------
__global__ __launch_bounds__(256) void k_prep(const float* __restrict__ Wn, const float* __restrict__ Wr,
                                              const float* __restrict__ b, const float* __restrict__ stats,
                                              const float* __restrict__ g, const float* __restrict__ be,
                                              float* __restrict__ wbuf, int din){
  __shared__ float sc[64], sh[64];
  int t = threadIdx.x;
  if (t < 64){
    float a = 1.0f, s0 = 0.0f;
    if (stats){
      float m = stats[t] * (1.0f/NN);
      float v = stats[64+t] * (1.0f/NN) - m*m;
      a  = g[t] * rsqrtf(v + EPSV);
      s0 = be[t] - m*a;
    }
    sc[t] = a; sh[t] = s0;
  }
  __syncthreads();
  for (int i = t; i < din*64; i += 256){
    int k = i >> 6;
    wbuf[i]          = sc[k]*Wn[i];
    wbuf[din*64 + i] = sc[k]*Wr[i];
  }
  if (t < 64){
    float accB = b ? b[t] : 0.0f;
    float accN = 0.0f;
    for (int k=0;k<din;k++){
      accB += sh[k]*Wr[k*64+t];
      accN += sh[k]*Wn[k*64+t];
    }
    wbuf[2*din*64 + t]      = accB;
    wbuf[2*din*64 + 64 + t] = accN;
  }
}

// ---------------- LDS-tiled conv GEMM ----------------
// Block = 256 thr, 64-node tile. Stage agg+x tiles into LDS with coalesced
// per-lane float4 loads; compute with broadcast ds_read_b128 + VGPR weights.
template<int DIN, int ACT, bool STATS>
__global__ __launch_bounds__(256, 1) void k_gemm_conv(const float* __restrict__ agg, const float* __restrict__ x,
                                                      const float* __restrict__ invdeg, const float* __restrict__ wbuf,
                                                      float* __restrict__ out, float* __restrict__ stats){
  __shared__ float sA[64*DIN];
  __shared__ float sX[64*DIN];
  __shared__ float sStat[512];
  const int tid  = threadIdx.x;
  const int lane = tid & 63;
  const int wv   = tid >> 6;
  const int n0   = blockIdx.x * 64;

  // stage: tile rows are contiguous in global (node-major)
  constexpr int NF4 = 64*DIN/4;              // float4 count per tile
  const float4* gA = (const float4*)(agg + (size_t)n0*DIN);
  const float4* gX = (const float4*)(x   + (size_t)n0*DIN);
  float4* s4A = (float4*)sA;
  float4* s4X = (float4*)sX;
  for (int i = tid; i < NF4; i += 256){ s4A[i] = gA[i]; s4X[i] = gX[i]; }

  float wn[DIN], wr[DIN];
  #pragma unroll
  for (int k=0;k<DIN;k++){
    wn[k] = wbuf[k*64+lane];
    wr[k] = wbuf[(DIN+k)*64+lane];
  }
  const float bj0 = wbuf[2*DIN*64+lane];
  const float bj1 = wbuf[2*DIN*64+64+lane];
  __syncthreads();

  float ls = 0.0f, lss = 0.0f;
  #pragma unroll 1
  for (int nn = wv*16; nn < wv*16+16; nn++){
    float accA = 0.0f, accX = 0.0f;
    if constexpr ((DIN & 3) == 0){
      const float4* rA = (const float4*)&sA[nn*DIN];
      const float4* rX = (const float4*)&sX[nn*DIN];
      #pragma unroll
      for (int c=0;c<DIN/4;c++){
        float4 a = rA[c], b = rX[c];
        accA = fmaf(a.x, wn[4*c+0], accA);
        accX = fmaf(b.x, wr[4*c+0], accX);
        accA = fmaf(a.y, wn[4*c+1], accA);
        accX = fmaf(b.y, wr[4*c+1], accX);
        accA = fmaf(a.z, wn[4*c+2], accA);
        accX = fmaf(b.z, wr[4*c+2], accX);
        accA = fmaf(a.w, wn[4*c+3], accA);
        accX = fmaf(b.w, wr[4*c+3], accX);
      }
    } else {
      #pragma unroll
      for (int k=0;k<DIN;k++){
        accA = fmaf(sA[nn*DIN+k], wn[k], accA);
        accX = fmaf(sX[nn*DIN+k], wr[k], accX);
      }
    }
    const int n = n0 + nn;
    float iv = invdeg[n];
    float t0 = (iv > 0.0f) ? fmaf(accA, iv, bj1) : 0.0f;
    float z = accX + bj0 + t0;
    if (ACT == 1) z = z > 0.0f ? z : 0.01f*z;
    if (ACT == 2) z = fmaxf(z, 0.0f);
    out[(size_t)n*64 + lane] = z;
    if (STATS){ ls += z; lss = fmaf(z,z,lss); }
  }
  if (STATS){
    sStat[wv*128 + lane]      = ls;
    sStat[wv*128 + 64 + lane] = lss;
    __syncthreads();
    if (tid < 128){
      float v = sStat[tid] + sStat[128+tid] + sStat[256+tid] + sStat[384+tid];
      atomicAdd(&stats[tid], v);
    }
  }
}

// ---------------- LDS-tiled linear ----------------
template<int DOUT, bool STATS, bool BIAS>
__global__ __launch_bounds__(256, 1) void k_gemm_lin(const float* __restrict__ x, const float* __restrict__ W,
                                                     const float* __restrict__ bias, float* __restrict__ out,
                                                     float* __restrict__ stats){
  __shared__ float sX[64*64];
  __shared__ float sStat[512];
  const int tid  = threadIdx.x;
  const int lane = tid & 63;
  const int wv   = tid >> 6;
  const int n0   = blockIdx.x * 64;

  const float4* gX = (const float4*)(x + (size_t)n0*64);
  float4* s4X = (float4*)sX;
  #pragma unroll
  for (int r=0;r<4;r++) s4X[r*256 + tid] = gX[r*256 + tid];

  float w[64];
  float bj = 0.0f;
  if (lane < DOUT){
    #pragma unroll
    for (int k=0;k<64;k++) w[k] = W[k*DOUT + lane];
    if (BIAS) bj = bias[lane];
  }
  __syncthreads();

  float ls = 0.0f, lss = 0.0f;
  if (lane < DOUT){
    #pragma unroll 1
    for (int nn = wv*16; nn < wv*16+16; nn++){
      const float4* rX = (const float4*)&sX[nn*64];
      float a0 = 0.0f, a1 = 0.0f;
      #pragma unroll
      for (int c=0;c<8;c++){
        float4 v0 = rX[2*c], v1 = rX[2*c+1];
        a0 = fmaf(v0.x, w[8*c+0], a0);
        a1 = fmaf(v1.x, w[8*c+4], a1);
        a0 = fmaf(v0.y, w[8*c+1], a0);
        a1 = fmaf(v1.y, w[8*c+5], a1);
        a0 = fmaf(v0.z, w[8*c+2], a0);
        a1 = fmaf(v1.z, w[8*c+6], a1);
        a0 = fmaf(v0.w, w[8*c+3], a0);
        a1 = fmaf(v1.w, w[8*c+7], a1);
      }
      float z = a0 + a1 + bj;
      out[(size_t)(n0+nn)*DOUT + lane] = z;
      if (STATS){ ls += z; lss = fmaf(z,z,lss); }
    }
  }
  if (STATS){
    sStat[wv*128 + lane]      = ls;
    sStat[wv*128 + 64 + lane] = lss;
    __syncthreads();
    if (tid < 128){
      float v = sStat[tid] + sStat[128+tid] + sStat[256+tid] + sStat[384+tid];
      atomicAdd(&stats[tid], v);
    }
  }
}

__global__ __launch_bounds__(256) void k_normrelu(float* __restrict__ h, const float* __restrict__ stats,
                                                  const float* __restrict__ g, const float* __restrict__ be){
  size_t idx = (size_t)blockIdx.x*256 + threadIdx.x;
  int f = (int)(idx & 63);
  float m = stats[f] * (1.0f/NN);
  float v = stats[64+f] * (1.0f/NN) - m*m;
  float a = g[f]*rsqrtf(v+EPSV);
  float b = be[f] - m*a;
  float z = h[idx];
  h[idx] = fmaxf(fmaf(a, z, b), 0.0f);
}

extern "C" void kernel_launch(void* const* d_in, const int* in_sizes, int n_in,
                              void* d_out, int out_size, void* d_ws, size_t ws_size,
                              hipStream_t stream){
  const float* x1  = (const float*)d_in[0];
  const int*   ei  = (const int*)d_in[1];
  const int* srcp = ei;
  const int* dstp = ei + EE;
  const float *Wn1=(const float*)d_in[2],  *Wr1=(const float*)d_in[3],  *b1=(const float*)d_in[4];
  const float *Wn2=(const float*)d_in[5],  *Wr2=(const float*)d_in[6],  *b2=(const float*)d_in[7];
  const float *Wn3=(const float*)d_in[8],  *Wr3=(const float*)d_in[9],  *b3=(const float*)d_in[10];
  const float *Wn4=(const float*)d_in[11], *Wr4=(const float*)d_in[12], *b4=(const float*)d_in[13];
  const float *g1=(const float*)d_in[14], *be1=(const float*)d_in[15];
  const float *g2=(const float*)d_in[16], *be2=(const float*)d_in[17];
  const float *g3=(const float*)d_in[18], *be3=(const float*)d_in[19];
  const float *Wm0=(const float*)d_in[20], *gm0=(const float*)d_in[21], *bem0=(const float*)d_in[22];
  const float *Wm1=(const float*)d_in[23], *gm1=(const float*)d_in[24], *bem1=(const float*)d_in[25];
  const float *Wm2=(const float*)d_in[26], *bm2=(const float*)d_in[27];
  float* out = (float*)d_out;

  char* ws = (char*)d_ws;
  int*   cnt     = (int*)(ws);
  int*   row_ptr = (int*)(ws + (1ull<<20));
  int*   cursor  = (int*)(ws + (2ull<<20));
  int*   pre     = (int*)(ws + (3ull<<20));
  int*   blksum  = (int*)(ws + (4ull<<20));
  float* invdeg  = (float*)(ws + (5ull<<20));
  int*   adj     = (int*)(ws + (6ull<<20));
  float* agg     = (float*)(ws + (12ull<<20));
  float* hA      = (float*)(ws + (43ull<<20));
  float* hB      = (float*)(ws + (74ull<<20));
  float* stats   = (float*)(ws + (105ull<<20));
  float* wbuf    = (float*)(ws + (105ull<<20) + 8192);

  hipMemsetAsync(cnt, 0, NN*sizeof(int), stream);
  hipMemsetAsync(stats, 0, 5*128*sizeof(float), stream);
  k_count<<<(EE+255)/256,256,0,stream>>>(dstp, cnt);
  k_scan1<<<NB_SCAN,256,0,stream>>>(cnt, pre, blksum);
  k_scan2<<<1,512,0,stream>>>(blksum);
  k_scan3<<<NB_SCAN,256,0,stream>>>(pre, blksum, cnt, row_ptr, cursor, invdeg);
  k_fill<<<(EE+255)/256,256,0,stream>>>(srcp, dstp, cursor, adj);

  k_gather14<<<2048,256,0,stream>>>(x1, row_ptr, cnt, adj, agg);
  k_prep<<<1,256,0,stream>>>(Wn1,Wr1,b1,nullptr,nullptr,nullptr,wbuf,14);
  k_gemm_conv<14,1,true><<<NTILE,256,0,stream>>>(agg,x1,invdeg,wbuf,hA,stats);

  k_gather64<<<2048,256,0,stream>>>(hA, row_ptr, cnt, adj, agg);
  k_prep<<<1,256,0,stream>>>(Wn2,Wr2,b2,stats,g1,be1,wbuf,64);
  k_gemm_conv<64,1,true><<<NTILE,256,0,stream>>>(agg,hA,invdeg,wbuf,hB,stats+128);

  k_gather64<<<2048,256,0,stream>>>(hB, row_ptr, cnt, adj, agg);
  k_prep<<<1,256,0,stream>>>(Wn3,Wr3,b3,stats+128,g2,be2,wbuf,64);
  k_gemm_conv<64,2,true><<<NTILE,256,0,stream>>>(agg,hB,invdeg,wbuf,hA,stats+256);

  k_gather64<<<2048,256,0,stream>>>(hA, row_ptr, cnt, adj, agg);
  k_prep<<<1,256,0,stream>>>(Wn4,Wr4,b4,stats+256,g3,be3,wbuf,64);
  k_gemm_conv<64,0,false><<<NTILE,256,0,stream>>>(agg,hA,invdeg,wbuf,hB,nullptr);

  k_gemm_lin<64,true,false><<<NTILE,256,0,stream>>>(hB,Wm0,nullptr,hA,stats+384);
  k_normrelu<<<(NN*64)/256,256,0,stream>>>(hA,stats+384,gm0,bem0);
  k_gemm_lin<64,true,false><<<NTILE,256,0,stream>>>(hA,Wm1,nullptr,hB,stats+512);
  k_normrelu<<<(NN*64)/256,256,0,stream>>>(hB,stats+512,gm1,bem1);
  k_gemm_lin<21,false,true><<<NTILE,256,0,stream>>>(hB,Wm2,bm2,out,nullptr);
}